// Round 7
// baseline (699.848 us; speedup 1.0000x reference)
//
#include <hip/hip_runtime.h>

#define NQ 512
#define NC 128
#define EC 32
#define OC 64

__device__ __forceinline__ float silu_f(float x) {
    return x / (1.0f + __expf(-x));
}

// ---------------------------------------------------------------------------
// Prepass: decode virtual_mask (unknown upload layout: u8 / int32 / f32).
// ---------------------------------------------------------------------------
__global__ void decode_mask_kernel(const unsigned char* __restrict__ raw,
                                   int* __restrict__ out, int n) {
    __shared__ int cntA, cntN;
    int t = threadIdx.x;
    if (t == 0) { cntA = 0; cntN = 0; }
    __syncthreads();
    int la = 0, ln = 0;
    for (int idx = t; idx < n; idx += blockDim.x) {
        unsigned char v = raw[idx];
        if (v) { if ((idx & 3) == 0) la++; else ln++; }
    }
    if (la) atomicAdd(&cntA, la);
    if (ln) atomicAdd(&cntN, ln);
    __syncthreads();
    int a = cntA, nn = cntN;
    for (int i = t; i < n; i += blockDim.x) {
        int v;
        if (a > 0 && nn == 0)      v = ((const int*)raw)[i];             // int32
        else if (a == 0)           v = (((const float*)raw)[i] != 0.0f); // f32
        else                       v = (raw[i] != 0);                    // u8
        out[i] = v;
    }
}

// ---------------------------------------------------------------------------
// N1: tiled masked row/col sums of edge. Block = one (b, 64x64 tile).
// Pass A (x_out partials): coalesced row reads, thread-local accumulators.
// Pass B (x_in partials): re-read tile (L2/L3-warm), lanes c=stride-1.
// wmask[a][bb] = causal(I0+a, J0+bb) precomputed once in LDS.
// ---------------------------------------------------------------------------
__global__ __launch_bounds__(256) void tile_sum_kernel(
    const float* __restrict__ edge, const int* __restrict__ block_id,
    const int* __restrict__ vmd,
    float* __restrict__ xin_part, float* __restrict__ xout_part) {
    __shared__ float wmask[64][64];
    __shared__ int idI[64], vmI[64], idJ[64], vmJ[64];

    const int t = threadIdx.x;
    const int bid = blockIdx.x;
    const int b = bid >> 6, It = (bid >> 3) & 7, Jt = bid & 7;
    const int I0 = It * 64, J0 = Jt * 64;

    if (t < 64)       { idI[t] = block_id[b * NQ + I0 + t]; vmI[t] = vmd[b * NQ + I0 + t]; }
    else if (t < 128) { int u = t - 64; idJ[u] = block_id[b * NQ + J0 + u]; vmJ[u] = vmd[b * NQ + J0 + u]; }
    __syncthreads();

    for (int idx = t; idx < 4096; idx += 256) {
        int a = idx >> 6, bb = idx & 63;
        int ida = idI[a], idb = idJ[bb];
        bool w = (ida >= 0) && (idb >= 0) &&
                 ((ida > idb) || (ida == idb && !vmI[a]));
        wmask[a][bb] = w ? 1.0f : 0.0f;
    }
    __syncthreads();

    const float* base = edge + (((size_t)(b * NQ) + I0) * NQ + J0) * EC;

    // ---- pass A: x_out partials (sum over rows a of this I-chunk) ----
    {
        const int bb1 = t >> 3, c0 = (t & 7) * 4;
        float a1x = 0.f, a1y = 0.f, a1z = 0.f, a1w = 0.f;
        float a2x = 0.f, a2y = 0.f, a2z = 0.f, a2w = 0.f;
        for (int a = 0; a < 64; ++a) {
            const float4* row = (const float4*)(base + (size_t)a * NQ * EC);
            float4 v1 = row[t];
            float4 v2 = row[t + 256];
            float w1 = wmask[a][bb1];
            float w2 = wmask[a][bb1 + 32];
            a1x += w1 * v1.x; a1y += w1 * v1.y; a1z += w1 * v1.z; a1w += w1 * v1.w;
            a2x += w2 * v2.x; a2y += w2 * v2.y; a2z += w2 * v2.z; a2w += w2 * v2.w;
        }
        float4 o1 = {a1x, a1y, a1z, a1w};
        float4 o2 = {a2x, a2y, a2z, a2w};
        *(float4*)(xout_part + ((size_t)(b * 8 + It) * NQ + J0 + bb1) * EC + c0) = o1;
        *(float4*)(xout_part + ((size_t)(b * 8 + It) * NQ + J0 + bb1 + 32) * EC + c0) = o2;
    }

    // ---- pass B: x_in partials (sum over cols bb of this J-chunk) ----
    {
        const int c = t & 31, g = t >> 5;
        float acc[8];
        #pragma unroll
        for (int k = 0; k < 8; ++k) acc[k] = 0.0f;
        #pragma unroll 1
        for (int k = 0; k < 8; ++k) {
            const int a = g + 8 * k;
            const float* rowa = base + (size_t)a * NQ * EC + c;
            float s = 0.f;
            #pragma unroll 4
            for (int bb = 0; bb < 64; ++bb) s += wmask[a][bb] * rowa[bb * EC];
            acc[k] = s;
        }
        #pragma unroll
        for (int k = 0; k < 8; ++k) {
            const int a = g + 8 * k;
            xin_part[((size_t)(b * 8 + Jt) * NQ + I0 + a) * EC + c] = acc[k];
        }
    }
}

// ---------------------------------------------------------------------------
// N2: combine tile partials + node GEMV chain. One block per (b,i), 128 thr.
// Also precomputes q1 = n1@W_f1, q2 = n2@W_f1 + b_f1 per node.
// ---------------------------------------------------------------------------
__global__ __launch_bounds__(128) void node2_kernel(
    const float* __restrict__ node, const int* __restrict__ block_id,
    const int* __restrict__ vmd,
    const float* __restrict__ xin_part, const float* __restrict__ xout_part,
    const float* __restrict__ W_nt, const float* __restrict__ b_nt,
    const float* __restrict__ W_n1, const float* __restrict__ b_n1,
    const float* __restrict__ W_f1, const float* __restrict__ b_f1,
    const float* __restrict__ W_no1, const float* __restrict__ b_no1,
    const float* __restrict__ g_no, const float* __restrict__ be_no,
    const float* __restrict__ W_no2, const float* __restrict__ b_no2,
    float* __restrict__ n_ws, float* __restrict__ q1_ws, float* __restrict__ q2_ws,
    float* __restrict__ out_node) {
    const int bi = blockIdx.x;
    const int b = bi >> 9, i = bi & (NQ - 1);
    const int t = threadIdx.x;

    __shared__ int   sid[NQ];
    __shared__ int   svm[NQ];
    __shared__ int   redi[128], redo[128];
    __shared__ float xcat[192];
    __shared__ float hbuf[128];
    __shared__ float red[128];
    __shared__ float nbuf[128];
    __shared__ float zbuf[128];

    for (int k = t; k < NQ; k += 128) {
        sid[k] = block_id[b * NQ + k];
        svm[k] = vmd[b * NQ + k];
    }
    __syncthreads();

    const int  id_i = sid[i];
    const int  vm_i = svm[i];
    const bool nm_i = (id_i >= 0);

    // counts
    int ci = 0, co = 0;
    #pragma unroll
    for (int r = 0; r < 4; ++r) {
        int j = t + 128 * r;
        int idj = sid[j];
        bool pv = nm_i && (idj >= 0);
        if (pv && ((id_i > idj) || (id_i == idj && !vm_i)))  ci++;
        if (pv && ((idj > id_i) || (idj == id_i && !svm[j]))) co++;
    }
    redi[t] = ci; redo[t] = co;
    __syncthreads();
    for (int s = 64; s > 0; s >>= 1) {
        if (t < s) { redi[t] += redi[t + s]; redo[t] += redo[t + s]; }
        __syncthreads();
    }
    const float cnt_in  = fmaxf((float)redi[0], 1.0f);
    const float cnt_out = fmaxf((float)redo[0], 1.0f);

    // xcat from partials
    if (t < 32) {
        float s = 0.f;
        #pragma unroll
        for (int q = 0; q < 8; ++q)
            s += xin_part[((size_t)(b * 8 + q) * NQ + i) * EC + t];
        xcat[t] = s / cnt_in;
    } else if (t < 64) {
        int c = t - 32;
        float s = 0.f;
        #pragma unroll
        for (int q = 0; q < 8; ++q)
            s += xout_part[((size_t)(b * 8 + q) * NQ + i) * EC + c];
        xcat[t] = s / cnt_out;
    }
    {
        float nv = node[(size_t)(b * NQ + i) * NC + t];
        xcat[64 + t] = nm_i ? nv : 0.0f;
    }
    __syncthreads();

    // h = silu(xcat @ W_nt + b_nt) * nm
    float acc = b_nt[t];
    #pragma unroll 4
    for (int k = 0; k < 192; ++k) acc += xcat[k] * W_nt[k * NC + t];
    float h = nm_i ? silu_f(acc) : 0.0f;
    hbuf[t] = h;
    __syncthreads();

    // n = h @ W_n1 + b_n1 ; u = h @ W_no1 + b_no1
    float accn = b_n1[t];
    float u = b_no1[t];
    #pragma unroll 4
    for (int k = 0; k < 128; ++k) {
        float hk = hbuf[k];
        accn += hk * W_n1[k * 128 + t];
        u    += hk * W_no1[k * 128 + t];
    }
    n_ws[(size_t)(b * NQ + i) * 128 + t] = accn;

    nbuf[t] = accn;
    red[t] = u;
    __syncthreads();

    // q1[c] = sum_k n1[k] W_f1[k,c]; q2[c] = b_f1[c] + sum_k n2[k] W_f1[k,c]
    {
        int cc = t & 63;
        const float* src = nbuf + ((t < 64) ? 0 : 64);
        float q = (t < 64) ? 0.0f : b_f1[cc];
        #pragma unroll 4
        for (int k = 0; k < 64; ++k) q += src[k] * W_f1[k * 64 + cc];
        float* dst = (t < 64) ? q1_ws : q2_ws;
        dst[(size_t)(b * NQ + i) * 64 + cc] = q;
    }

    // LayerNorm over 128 channels (across threads)
    for (int s = 64; s > 0; s >>= 1) { if (t < s) red[t] += red[t + s]; __syncthreads(); }
    float m = red[0] * (1.0f / 128.0f);
    __syncthreads();
    float d = u - m;
    red[t] = d * d;
    __syncthreads();
    for (int s = 64; s > 0; s >>= 1) { if (t < s) red[t] += red[t + s]; __syncthreads(); }
    float var = red[0] * (1.0f / 128.0f);
    float z = silu_f(d * rsqrtf(var + 1e-5f) * g_no[t] + be_no[t]);
    zbuf[t] = z;
    __syncthreads();

    if (t < 10) {
        float o = b_no2[t];
        #pragma unroll 4
        for (int k2 = 0; k2 < 128; ++k2) o += zbuf[k2] * W_no2[k2 * 10 + t];
        out_node[(size_t)(b * NQ + i) * 10 + t] = nm_i ? o : 0.0f;
    }
}

// ---------------------------------------------------------------------------
// Edge path, wave-specialized: block = 256 threads = 4 waves, 64 pairs.
// Wave w owns channels [16w,16w+16); lane p owns pair p. Weights are
// wave-uniform -> SGPR. einT padded to stride 66 (staging writes 2-way = free,
// reads conflict-free); red2/oBuf overlay the einT buffer -> LDS 24.5KB,
// 6 blocks/CU.
// ---------------------------------------------------------------------------
__global__ __launch_bounds__(256, 6) void edge_kernel(
    const float* __restrict__ edge, const int* __restrict__ block_id,
    const int* __restrict__ vmd, const float* __restrict__ n_ws,
    const float* __restrict__ q1_ws, const float* __restrict__ q2_ws,
    const float* __restrict__ W_e1, const float* __restrict__ b_e1,
    const float* __restrict__ W_f2, const float* __restrict__ b_f2,
    const float* __restrict__ W_eo1, const float* __restrict__ b_eo1,
    const float* __restrict__ g_eo, const float* __restrict__ be_eo,
    const float* __restrict__ W_eo2, const float* __restrict__ b_eo2,
    float* __restrict__ out_edge) {
    __shared__ float e0T[64][64];    // e0 / es, transposed [c][p]
    __shared__ float smA[32 * 66];   // einT (stride 66); later red2(512f)+oBuf(1280f)
    float* red2 = smA;               // [2][4][64]
    float* oBuf = smA + 512;         // [4][64][5]

    const int tid = threadIdx.x;
    const int p = tid & 63;
    const int w = __builtin_amdgcn_readfirstlane(tid >> 6);
    const int bid = blockIdx.x;

    int b, ib0, jb0;
    bool tail;
    if (bid < 8192) {
        b = bid >> 11;
        int rem = bid & 2047;
        ib0 = rem >> 2;            // fixed i
        jb0 = ib0 + (rem & 3) * 64;
        tail = false;
    } else {
        int t2 = bid - 8192;
        b = t2 >> 2;
        ib0 = (t2 & 3) * 64;       // i = ib0 + p
        jb0 = 0;
        tail = true;
    }
    const int i_p = tail ? (ib0 + p) : ib0;
    const int j_p = tail ? (i_p + 256) : ((jb0 + p) & (NQ - 1));

    const float* nb0 = n_ws  + (size_t)b * NQ * 128;
    const float* q1t = q1_ws + (size_t)b * NQ * 64;
    const float* q2t = q2_ws + (size_t)b * NQ * 64;

    float es[16];
    #pragma unroll
    for (int u = 0; u < 16; ++u) es[u] = 0.0f;

    #pragma unroll 1
    for (int d = 0; d < 2; ++d) {
        // ---- stage ein (transposed, stride 66) ----
        {
            const int pr = tid >> 2, u = tid & 3;
            const int i_r = tail ? (ib0 + pr) : ib0;
            const int j_r = tail ? (i_r + 256) : ((jb0 + pr) & (NQ - 1));
            const size_t rowbase = d == 0
                ? (((size_t)(b * NQ) + i_r) * NQ + j_r) * EC
                : (((size_t)(b * NQ) + j_r) * NQ + i_r) * EC;
            const float4* src = (const float4*)(edge + rowbase);
            float4 v0 = src[u];
            float4 v1 = src[u + 4];
            smA[(4 * u + 0) * 66 + pr] = v0.x; smA[(4 * u + 1) * 66 + pr] = v0.y;
            smA[(4 * u + 2) * 66 + pr] = v0.z; smA[(4 * u + 3) * 66 + pr] = v0.w;
            smA[(4 * (u + 4) + 0) * 66 + pr] = v1.x; smA[(4 * (u + 4) + 1) * 66 + pr] = v1.y;
            smA[(4 * (u + 4) + 2) * 66 + pr] = v1.z; smA[(4 * (u + 4) + 3) * 66 + pr] = v1.w;
        }
        __syncthreads();

        // ---- phase 1: e0 chunk = ein @ W_e1 + b_e1 (SGPR weights) ----
        float e0c[16];
        #pragma unroll
        for (int u = 0; u < 16; ++u) e0c[u] = b_e1[w * 16 + u];
        #pragma unroll 4
        for (int k = 0; k < EC; ++k) {
            float ek = smA[k * 66 + p];
            const float* wr = W_e1 + k * OC + w * 16;
            #pragma unroll
            for (int u = 0; u < 16; ++u) e0c[u] += ek * wr[u];
        }
        #pragma unroll
        for (int u = 0; u < 16; ++u) e0T[w * 16 + u][p] = e0c[u];
        __syncthreads();

        // ---- phase 2: t2 chunk = e0 @ W_f2 + b_f2 (full-k from LDS) ----
        float t2a[16];
        #pragma unroll
        for (int u = 0; u < 16; ++u) t2a[u] = b_f2[w * 16 + u];
        #pragma unroll 4
        for (int k = 0; k < OC; ++k) {
            float e0k = e0T[k][p];
            const float* wr = W_f2 + k * OC + w * 16;
            #pragma unroll
            for (int u = 0; u < 16; ++u) t2a[u] += e0k * wr[u];
        }

        // ---- combine: es += silu(np + e0 + silu(q1+q2)*silu(t2)) ----
        {
            const int ja = d == 0 ? j_p : i_p;   // feeds n1/q1
            const int ib = d == 0 ? i_p : j_p;   // feeds n2/q2
            const float* pq1 = q1t + (size_t)ja * 64 + w * 16;
            const float* pq2 = q2t + (size_t)ib * 64 + w * 16;
            const float* pn1 = nb0 + (size_t)ja * 128 + w * 16;
            const float* pn2 = nb0 + (size_t)ib * 128 + 64 + w * 16;
            #pragma unroll
            for (int v4 = 0; v4 < 4; ++v4) {
                float4 a1 = ((const float4*)pq1)[v4];
                float4 a2 = ((const float4*)pq2)[v4];
                float4 b1 = ((const float4*)pn1)[v4];
                float4 b2 = ((const float4*)pn2)[v4];
                float q1r[4] = {a1.x, a1.y, a1.z, a1.w};
                float q2r[4] = {a2.x, a2.y, a2.z, a2.w};
                float n1r[4] = {b1.x, b1.y, b1.z, b1.w};
                float n2r[4] = {b2.x, b2.y, b2.z, b2.w};
                #pragma unroll
                for (int r = 0; r < 4; ++r) {
                    int c = v4 * 4 + r;
                    float t1 = silu_f(q1r[r] + q2r[r]);
                    float t2 = silu_f(t2a[c]);
                    es[c] += silu_f(n1r[r] + n2r[r] + e0c[c] + t1 * t2);
                }
            }
        }
        __syncthreads();
    }

    // ---- write es (transposed) for the eo1 full-k GEMV ----
    #pragma unroll
    for (int u = 0; u < 16; ++u) e0T[w * 16 + u][p] = es[u];
    __syncthreads();

    // ---- eo1: y chunk (8 channels per wave) = es @ W_eo1 + b_eo1 ----
    const int c0 = w * 8;
    float y[8];
    #pragma unroll
    for (int u = 0; u < 8; ++u) y[u] = b_eo1[c0 + u];
    #pragma unroll 4
    for (int k = 0; k < OC; ++k) {
        float esk = e0T[k][p];
        const float* wr = W_eo1 + k * 32 + c0;
        #pragma unroll
        for (int u = 0; u < 8; ++u) y[u] += esk * wr[u];
    }

    // ---- LayerNorm partials across waves ----
    float s1 = 0.f, s2 = 0.f;
    #pragma unroll
    for (int u = 0; u < 8; ++u) { s1 += y[u]; s2 += y[u] * y[u]; }
    red2[0 * 256 + w * 64 + p] = s1;
    red2[1 * 256 + w * 64 + p] = s2;
    __syncthreads();
    float S1 = red2[p] + red2[64 + p] + red2[128 + p] + red2[192 + p];
    float S2 = red2[256 + p] + red2[320 + p] + red2[384 + p] + red2[448 + p];
    float mean = S1 * (1.0f / 32.0f);
    float var  = S2 * (1.0f / 32.0f) - mean * mean;
    float rs = rsqrtf(var + 1e-5f);

    // ---- z + eo2 partial ----
    float o[5] = {0.f, 0.f, 0.f, 0.f, 0.f};
    #pragma unroll
    for (int u = 0; u < 8; ++u) {
        float z = silu_f((y[u] - mean) * rs * g_eo[c0 + u] + be_eo[c0 + u]);
        const float* wr = W_eo2 + (c0 + u) * 5;
        #pragma unroll
        for (int q = 0; q < 5; ++q) o[q] += z * wr[q];
    }
    #pragma unroll
    for (int q = 0; q < 5; ++q) oBuf[(w * 64 + p) * 5 + q] = o[q];
    __syncthreads();

    // ---- wave 0: sum partials, mask, write both (i,j) and (j,i) ----
    if (w == 0) {
        const int id_i = block_id[b * NQ + i_p], id_j = block_id[b * NQ + j_p];
        const int vm_i = vmd[b * NQ + i_p],      vm_j = vmd[b * NQ + j_p];
        const bool em = (id_i >= 0) && (id_j >= 0) &&
                        ((id_i != id_j) || (!vm_i) || (!vm_j));
        float* oe1 = out_edge + (((size_t)(b * NQ) + i_p) * NQ + j_p) * 5;
        float* oe2 = out_edge + (((size_t)(b * NQ) + j_p) * NQ + i_p) * 5;
        #pragma unroll
        for (int q = 0; q < 5; ++q) {
            float vq = b_eo2[q] + oBuf[(0 * 64 + p) * 5 + q] + oBuf[(1 * 64 + p) * 5 + q]
                                + oBuf[(2 * 64 + p) * 5 + q] + oBuf[(3 * 64 + p) * 5 + q];
            vq = em ? vq : 0.0f;
            oe1[q] = vq;
            oe2[q] = vq;
        }
    }
}

extern "C" void kernel_launch(void* const* d_in, const int* in_sizes, int n_in,
                              void* d_out, int out_size, void* d_ws, size_t ws_size,
                              hipStream_t stream) {
    const float* node     = (const float*)d_in[0];
    const float* edge     = (const float*)d_in[1];
    const int*   block_id = (const int*)d_in[2];
    const void*  vm_raw   = d_in[3];
    const float* W_nt  = (const float*)d_in[4];
    const float* b_nt  = (const float*)d_in[5];
    const float* W_n1  = (const float*)d_in[6];
    const float* b_n1  = (const float*)d_in[7];
    const float* W_e1  = (const float*)d_in[8];
    const float* b_e1  = (const float*)d_in[9];
    const float* W_f1  = (const float*)d_in[10];
    const float* b_f1  = (const float*)d_in[11];
    const float* W_f2  = (const float*)d_in[12];
    const float* b_f2  = (const float*)d_in[13];
    const float* W_no1 = (const float*)d_in[14];
    const float* b_no1 = (const float*)d_in[15];
    const float* g_no  = (const float*)d_in[16];
    const float* be_no = (const float*)d_in[17];
    const float* W_no2 = (const float*)d_in[18];
    const float* b_no2 = (const float*)d_in[19];
    const float* W_eo1 = (const float*)d_in[20];
    const float* b_eo1 = (const float*)d_in[21];
    const float* g_eo  = (const float*)d_in[22];
    const float* be_eo = (const float*)d_in[23];
    const float* W_eo2 = (const float*)d_in[24];
    const float* b_eo2 = (const float*)d_in[25];

    char* ws = (char*)d_ws;
    int*   vmd   = (int*)ws;                                   // 8 KB
    float* n_ws  = (float*)(ws + 8192);                        // 1 MB
    float* q1_ws = (float*)(ws + 8192 + (1 << 20));            // 512 KB
    float* q2_ws = (float*)(ws + 8192 + (1 << 20) + (512 << 10)); // 512 KB
    float* xin_part  = (float*)(ws + 8192 + (2 << 20));        // 2 MB
    float* xout_part = (float*)(ws + 8192 + (4 << 20));        // 2 MB
    float* out_node = (float*)d_out;
    float* out_edge = out_node + 4 * 512 * 10;

    decode_mask_kernel<<<1, 256, 0, stream>>>((const unsigned char*)vm_raw, vmd, 4 * 512);
    tile_sum_kernel<<<256, 256, 0, stream>>>(edge, block_id, vmd, xin_part, xout_part);
    node2_kernel<<<4 * 512, 128, 0, stream>>>(
        node, block_id, vmd, xin_part, xout_part,
        W_nt, b_nt, W_n1, b_n1, W_f1, b_f1, W_no1, b_no1, g_no, be_no, W_no2, b_no2,
        n_ws, q1_ws, q2_ws, out_node);
    edge_kernel<<<8192 + 16, 256, 0, stream>>>(
        edge, block_id, vmd, n_ws, q1_ws, q2_ws,
        W_e1, b_e1, W_f2, b_f2,
        W_eo1, b_eo1, g_eo, be_eo, W_eo2, b_eo2, out_edge);
}

// Round 8
// 594.972 us; speedup vs baseline: 1.1763x; 1.1763x over previous
//
#include <hip/hip_runtime.h>

#define NQ 512
#define NC 128
#define EC 32
#define OC 64

__device__ __forceinline__ float silu_f(float x) {
    return x / (1.0f + __expf(-x));
}

// ---------------------------------------------------------------------------
// Prepass: decode virtual_mask (unknown upload layout: u8 / int32 / f32).
// ---------------------------------------------------------------------------
__global__ void decode_mask_kernel(const unsigned char* __restrict__ raw,
                                   int* __restrict__ out, int n) {
    __shared__ int cntA, cntN;
    int t = threadIdx.x;
    if (t == 0) { cntA = 0; cntN = 0; }
    __syncthreads();
    int la = 0, ln = 0;
    for (int idx = t; idx < n; idx += blockDim.x) {
        unsigned char v = raw[idx];
        if (v) { if ((idx & 3) == 0) la++; else ln++; }
    }
    if (la) atomicAdd(&cntA, la);
    if (ln) atomicAdd(&cntN, ln);
    __syncthreads();
    int a = cntA, nn = cntN;
    for (int i = t; i < n; i += blockDim.x) {
        int v;
        if (a > 0 && nn == 0)      v = ((const int*)raw)[i];             // int32
        else if (a == 0)           v = (((const float*)raw)[i] != 0.0f); // f32
        else                       v = (raw[i] != 0);                    // u8
        out[i] = v;
    }
}

// ---------------------------------------------------------------------------
// N1: tiled masked row/col sums of edge. Block = one (b, 64x64 tile),
// 1024 threads (16 waves/CU -> latency hiding; grid 256 = 1 block/CU).
// Pass A (x_out partials): coalesced float4 streaming, a-range split across
// two 512-thread halves, combined in LDS.
// Pass B (x_in partials): re-read tile (L2-warm), 2 rows/thread.
// ---------------------------------------------------------------------------
__global__ __launch_bounds__(1024) void tile_sum_kernel(
    const float* __restrict__ edge, const int* __restrict__ block_id,
    const int* __restrict__ vmd,
    float* __restrict__ xin_part, float* __restrict__ xout_part) {
    __shared__ float wmask[64][64];
    __shared__ int idI[64], vmI[64], idJ[64], vmJ[64];
    __shared__ float4 partA[512];

    const int t = threadIdx.x;
    const int bid = blockIdx.x;
    const int b = bid >> 6, It = (bid >> 3) & 7, Jt = bid & 7;
    const int I0 = It * 64, J0 = Jt * 64;

    if (t < 64)       { idI[t] = block_id[b * NQ + I0 + t]; vmI[t] = vmd[b * NQ + I0 + t]; }
    else if (t < 128) { int u = t - 64; idJ[u] = block_id[b * NQ + J0 + u]; vmJ[u] = vmd[b * NQ + J0 + u]; }
    __syncthreads();

    for (int idx = t; idx < 4096; idx += 1024) {
        int a = idx >> 6, bb = idx & 63;
        int ida = idI[a], idb = idJ[bb];
        bool w = (ida >= 0) && (idb >= 0) &&
                 ((ida > idb) || (ida == idb && !vmI[a]));
        wmask[a][bb] = w ? 1.0f : 0.0f;
    }
    __syncthreads();

    const float* base = edge + (((size_t)(b * NQ) + I0) * NQ + J0) * EC;

    // ---- pass A: x_out partials (sum over rows a of this I-chunk) ----
    {
        const int tc = t & 511;           // column unit: bb = tc>>3, c0 = (tc&7)*4
        const int h  = t >> 9;            // a-half
        const int bb = tc >> 3, c0 = (tc & 7) * 4;
        float4 acc = {0.f, 0.f, 0.f, 0.f};
        const int a0 = h * 32;
        for (int k = 0; k < 32; ++k) {
            const int a = a0 + k;
            const float4* row = (const float4*)(base + (size_t)a * NQ * EC);
            float4 v = row[tc];
            float w = wmask[a][bb];
            acc.x += w * v.x; acc.y += w * v.y; acc.z += w * v.z; acc.w += w * v.w;
        }
        if (h == 1) partA[tc] = acc;
        __syncthreads();
        if (h == 0) {
            float4 p = partA[tc];
            acc.x += p.x; acc.y += p.y; acc.z += p.z; acc.w += p.w;
            *(float4*)(xout_part + ((size_t)(b * 8 + It) * NQ + J0 + bb) * EC + c0) = acc;
        }
    }
    __syncthreads();

    // ---- pass B: x_in partials (sum over cols bb of this J-chunk) ----
    {
        const int c = t & 31, g = t >> 5;   // g in [0,32)
        #pragma unroll
        for (int half = 0; half < 2; ++half) {
            const int a = g + 32 * half;
            const float* rowa = base + (size_t)a * NQ * EC + c;
            float s = 0.f;
            #pragma unroll 4
            for (int bb = 0; bb < 64; ++bb) s += wmask[a][bb] * rowa[bb * EC];
            xin_part[((size_t)(b * 8 + Jt) * NQ + I0 + a) * EC + c] = s;
        }
    }
}

// ---------------------------------------------------------------------------
// N2: combine tile partials + node GEMV chain. One block per (b,i), 128 thr.
// Also precomputes q1 = n1@W_f1, q2 = n2@W_f1 + b_f1 per node.
// ---------------------------------------------------------------------------
__global__ __launch_bounds__(128) void node2_kernel(
    const float* __restrict__ node, const int* __restrict__ block_id,
    const int* __restrict__ vmd,
    const float* __restrict__ xin_part, const float* __restrict__ xout_part,
    const float* __restrict__ W_nt, const float* __restrict__ b_nt,
    const float* __restrict__ W_n1, const float* __restrict__ b_n1,
    const float* __restrict__ W_f1, const float* __restrict__ b_f1,
    const float* __restrict__ W_no1, const float* __restrict__ b_no1,
    const float* __restrict__ g_no, const float* __restrict__ be_no,
    const float* __restrict__ W_no2, const float* __restrict__ b_no2,
    float* __restrict__ n_ws, float* __restrict__ q1_ws, float* __restrict__ q2_ws,
    float* __restrict__ out_node) {
    const int bi = blockIdx.x;
    const int b = bi >> 9, i = bi & (NQ - 1);
    const int t = threadIdx.x;

    __shared__ int   sid[NQ];
    __shared__ int   svm[NQ];
    __shared__ int   redi[128], redo[128];
    __shared__ float xcat[192];
    __shared__ float hbuf[128];
    __shared__ float red[128];
    __shared__ float nbuf[128];
    __shared__ float zbuf[128];

    for (int k = t; k < NQ; k += 128) {
        sid[k] = block_id[b * NQ + k];
        svm[k] = vmd[b * NQ + k];
    }
    __syncthreads();

    const int  id_i = sid[i];
    const int  vm_i = svm[i];
    const bool nm_i = (id_i >= 0);

    // counts
    int ci = 0, co = 0;
    #pragma unroll
    for (int r = 0; r < 4; ++r) {
        int j = t + 128 * r;
        int idj = sid[j];
        bool pv = nm_i && (idj >= 0);
        if (pv && ((id_i > idj) || (id_i == idj && !vm_i)))  ci++;
        if (pv && ((idj > id_i) || (idj == id_i && !svm[j]))) co++;
    }
    redi[t] = ci; redo[t] = co;
    __syncthreads();
    for (int s = 64; s > 0; s >>= 1) {
        if (t < s) { redi[t] += redi[t + s]; redo[t] += redo[t + s]; }
        __syncthreads();
    }
    const float cnt_in  = fmaxf((float)redi[0], 1.0f);
    const float cnt_out = fmaxf((float)redo[0], 1.0f);

    // xcat from partials
    if (t < 32) {
        float s = 0.f;
        #pragma unroll
        for (int q = 0; q < 8; ++q)
            s += xin_part[((size_t)(b * 8 + q) * NQ + i) * EC + t];
        xcat[t] = s / cnt_in;
    } else if (t < 64) {
        int c = t - 32;
        float s = 0.f;
        #pragma unroll
        for (int q = 0; q < 8; ++q)
            s += xout_part[((size_t)(b * 8 + q) * NQ + i) * EC + c];
        xcat[t] = s / cnt_out;
    }
    {
        float nv = node[(size_t)(b * NQ + i) * NC + t];
        xcat[64 + t] = nm_i ? nv : 0.0f;
    }
    __syncthreads();

    // h = silu(xcat @ W_nt + b_nt) * nm
    float acc = b_nt[t];
    #pragma unroll 4
    for (int k = 0; k < 192; ++k) acc += xcat[k] * W_nt[k * NC + t];
    float h = nm_i ? silu_f(acc) : 0.0f;
    hbuf[t] = h;
    __syncthreads();

    // n = h @ W_n1 + b_n1 ; u = h @ W_no1 + b_no1
    float accn = b_n1[t];
    float u = b_no1[t];
    #pragma unroll 4
    for (int k = 0; k < 128; ++k) {
        float hk = hbuf[k];
        accn += hk * W_n1[k * 128 + t];
        u    += hk * W_no1[k * 128 + t];
    }
    n_ws[(size_t)(b * NQ + i) * 128 + t] = accn;

    nbuf[t] = accn;
    red[t] = u;
    __syncthreads();

    // q1[c] = sum_k n1[k] W_f1[k,c]; q2[c] = b_f1[c] + sum_k n2[k] W_f1[k,c]
    {
        int cc = t & 63;
        const float* src = nbuf + ((t < 64) ? 0 : 64);
        float q = (t < 64) ? 0.0f : b_f1[cc];
        #pragma unroll 4
        for (int k = 0; k < 64; ++k) q += src[k] * W_f1[k * 64 + cc];
        float* dst = (t < 64) ? q1_ws : q2_ws;
        dst[(size_t)(b * NQ + i) * 64 + cc] = q;
    }

    // LayerNorm over 128 channels (across threads)
    for (int s = 64; s > 0; s >>= 1) { if (t < s) red[t] += red[t + s]; __syncthreads(); }
    float m = red[0] * (1.0f / 128.0f);
    __syncthreads();
    float d = u - m;
    red[t] = d * d;
    __syncthreads();
    for (int s = 64; s > 0; s >>= 1) { if (t < s) red[t] += red[t + s]; __syncthreads(); }
    float var = red[0] * (1.0f / 128.0f);
    float z = silu_f(d * rsqrtf(var + 1e-5f) * g_no[t] + be_no[t]);
    zbuf[t] = z;
    __syncthreads();

    if (t < 10) {
        float o = b_no2[t];
        #pragma unroll 4
        for (int k2 = 0; k2 < 128; ++k2) o += zbuf[k2] * W_no2[k2 * 10 + t];
        out_node[(size_t)(b * NQ + i) * 10 + t] = nm_i ? o : 0.0f;
    }
}

// ---------------------------------------------------------------------------
// Edge path, wave-specialized: block = 256 threads = 4 waves, 64 pairs.
// Wave w owns channels [16w,16w+16); lane p owns pair p. Weights are
// wave-uniform -> SGPR. einT padded to stride 66 (staging writes 2-way = free,
// reads conflict-free); red2/oBuf overlay the einT buffer -> LDS 24.5KB.
// launch_bounds min-waves kept at 4: 6 forced VGPR<52 and spilled es[16]
// (R7: WRITE_SIZE +107MB, dur +26%).
// ---------------------------------------------------------------------------
__global__ __launch_bounds__(256, 4) void edge_kernel(
    const float* __restrict__ edge, const int* __restrict__ block_id,
    const int* __restrict__ vmd, const float* __restrict__ n_ws,
    const float* __restrict__ q1_ws, const float* __restrict__ q2_ws,
    const float* __restrict__ W_e1, const float* __restrict__ b_e1,
    const float* __restrict__ W_f2, const float* __restrict__ b_f2,
    const float* __restrict__ W_eo1, const float* __restrict__ b_eo1,
    const float* __restrict__ g_eo, const float* __restrict__ be_eo,
    const float* __restrict__ W_eo2, const float* __restrict__ b_eo2,
    float* __restrict__ out_edge) {
    __shared__ float e0T[64][64];    // e0 / es, transposed [c][p]
    __shared__ float smA[32 * 66];   // einT (stride 66); later red2(512f)+oBuf(1280f)
    float* red2 = smA;               // [2][4][64]
    float* oBuf = smA + 512;         // [4][64][5]

    const int tid = threadIdx.x;
    const int p = tid & 63;
    const int w = __builtin_amdgcn_readfirstlane(tid >> 6);
    const int bid = blockIdx.x;

    int b, ib0, jb0;
    bool tail;
    if (bid < 8192) {
        b = bid >> 11;
        int rem = bid & 2047;
        ib0 = rem >> 2;            // fixed i
        jb0 = ib0 + (rem & 3) * 64;
        tail = false;
    } else {
        int t2 = bid - 8192;
        b = t2 >> 2;
        ib0 = (t2 & 3) * 64;       // i = ib0 + p
        jb0 = 0;
        tail = true;
    }
    const int i_p = tail ? (ib0 + p) : ib0;
    const int j_p = tail ? (i_p + 256) : ((jb0 + p) & (NQ - 1));

    const float* nb0 = n_ws  + (size_t)b * NQ * 128;
    const float* q1t = q1_ws + (size_t)b * NQ * 64;
    const float* q2t = q2_ws + (size_t)b * NQ * 64;

    float es[16];
    #pragma unroll
    for (int u = 0; u < 16; ++u) es[u] = 0.0f;

    #pragma unroll 1
    for (int d = 0; d < 2; ++d) {
        // ---- stage ein (transposed, stride 66) ----
        {
            const int pr = tid >> 2, u = tid & 3;
            const int i_r = tail ? (ib0 + pr) : ib0;
            const int j_r = tail ? (i_r + 256) : ((jb0 + pr) & (NQ - 1));
            const size_t rowbase = d == 0
                ? (((size_t)(b * NQ) + i_r) * NQ + j_r) * EC
                : (((size_t)(b * NQ) + j_r) * NQ + i_r) * EC;
            const float4* src = (const float4*)(edge + rowbase);
            float4 v0 = src[u];
            float4 v1 = src[u + 4];
            smA[(4 * u + 0) * 66 + pr] = v0.x; smA[(4 * u + 1) * 66 + pr] = v0.y;
            smA[(4 * u + 2) * 66 + pr] = v0.z; smA[(4 * u + 3) * 66 + pr] = v0.w;
            smA[(4 * (u + 4) + 0) * 66 + pr] = v1.x; smA[(4 * (u + 4) + 1) * 66 + pr] = v1.y;
            smA[(4 * (u + 4) + 2) * 66 + pr] = v1.z; smA[(4 * (u + 4) + 3) * 66 + pr] = v1.w;
        }
        __syncthreads();

        // ---- phase 1: e0 chunk = ein @ W_e1 + b_e1 (SGPR weights) ----
        float e0c[16];
        #pragma unroll
        for (int u = 0; u < 16; ++u) e0c[u] = b_e1[w * 16 + u];
        #pragma unroll 4
        for (int k = 0; k < EC; ++k) {
            float ek = smA[k * 66 + p];
            const float* wr = W_e1 + k * OC + w * 16;
            #pragma unroll
            for (int u = 0; u < 16; ++u) e0c[u] += ek * wr[u];
        }
        #pragma unroll
        for (int u = 0; u < 16; ++u) e0T[w * 16 + u][p] = e0c[u];
        __syncthreads();

        // ---- phase 2: t2 chunk = e0 @ W_f2 + b_f2 (full-k from LDS) ----
        float t2a[16];
        #pragma unroll
        for (int u = 0; u < 16; ++u) t2a[u] = b_f2[w * 16 + u];
        #pragma unroll 4
        for (int k = 0; k < OC; ++k) {
            float e0k = e0T[k][p];
            const float* wr = W_f2 + k * OC + w * 16;
            #pragma unroll
            for (int u = 0; u < 16; ++u) t2a[u] += e0k * wr[u];
        }

        // ---- combine: es += silu(np + e0 + silu(q1+q2)*silu(t2)) ----
        {
            const int ja = d == 0 ? j_p : i_p;   // feeds n1/q1
            const int ib = d == 0 ? i_p : j_p;   // feeds n2/q2
            const float* pq1 = q1t + (size_t)ja * 64 + w * 16;
            const float* pq2 = q2t + (size_t)ib * 64 + w * 16;
            const float* pn1 = nb0 + (size_t)ja * 128 + w * 16;
            const float* pn2 = nb0 + (size_t)ib * 128 + 64 + w * 16;
            #pragma unroll
            for (int v4 = 0; v4 < 4; ++v4) {
                float4 a1 = ((const float4*)pq1)[v4];
                float4 a2 = ((const float4*)pq2)[v4];
                float4 b1 = ((const float4*)pn1)[v4];
                float4 b2 = ((const float4*)pn2)[v4];
                float q1r[4] = {a1.x, a1.y, a1.z, a1.w};
                float q2r[4] = {a2.x, a2.y, a2.z, a2.w};
                float n1r[4] = {b1.x, b1.y, b1.z, b1.w};
                float n2r[4] = {b2.x, b2.y, b2.z, b2.w};
                #pragma unroll
                for (int r = 0; r < 4; ++r) {
                    int c = v4 * 4 + r;
                    float t1 = silu_f(q1r[r] + q2r[r]);
                    float t2 = silu_f(t2a[c]);
                    es[c] += silu_f(n1r[r] + n2r[r] + e0c[c] + t1 * t2);
                }
            }
        }
        __syncthreads();
    }

    // ---- write es (transposed) for the eo1 full-k GEMV ----
    #pragma unroll
    for (int u = 0; u < 16; ++u) e0T[w * 16 + u][p] = es[u];
    __syncthreads();

    // ---- eo1: y chunk (8 channels per wave) = es @ W_eo1 + b_eo1 ----
    const int c0 = w * 8;
    float y[8];
    #pragma unroll
    for (int u = 0; u < 8; ++u) y[u] = b_eo1[c0 + u];
    #pragma unroll 4
    for (int k = 0; k < OC; ++k) {
        float esk = e0T[k][p];
        const float* wr = W_eo1 + k * 32 + c0;
        #pragma unroll
        for (int u = 0; u < 8; ++u) y[u] += esk * wr[u];
    }

    // ---- LayerNorm partials across waves ----
    float s1 = 0.f, s2 = 0.f;
    #pragma unroll
    for (int u = 0; u < 8; ++u) { s1 += y[u]; s2 += y[u] * y[u]; }
    red2[0 * 256 + w * 64 + p] = s1;
    red2[1 * 256 + w * 64 + p] = s2;
    __syncthreads();
    float S1 = red2[p] + red2[64 + p] + red2[128 + p] + red2[192 + p];
    float S2 = red2[256 + p] + red2[320 + p] + red2[384 + p] + red2[448 + p];
    float mean = S1 * (1.0f / 32.0f);
    float var  = S2 * (1.0f / 32.0f) - mean * mean;
    float rs = rsqrtf(var + 1e-5f);

    // ---- z + eo2 partial ----
    float o[5] = {0.f, 0.f, 0.f, 0.f, 0.f};
    #pragma unroll
    for (int u = 0; u < 8; ++u) {
        float z = silu_f((y[u] - mean) * rs * g_eo[c0 + u] + be_eo[c0 + u]);
        const float* wr = W_eo2 + (c0 + u) * 5;
        #pragma unroll
        for (int q = 0; q < 5; ++q) o[q] += z * wr[q];
    }
    #pragma unroll
    for (int q = 0; q < 5; ++q) oBuf[(w * 64 + p) * 5 + q] = o[q];
    __syncthreads();

    // ---- wave 0: sum partials, mask, write both (i,j) and (j,i) ----
    if (w == 0) {
        const int id_i = block_id[b * NQ + i_p], id_j = block_id[b * NQ + j_p];
        const int vm_i = vmd[b * NQ + i_p],      vm_j = vmd[b * NQ + j_p];
        const bool em = (id_i >= 0) && (id_j >= 0) &&
                        ((id_i != id_j) || (!vm_i) || (!vm_j));
        float* oe1 = out_edge + (((size_t)(b * NQ) + i_p) * NQ + j_p) * 5;
        float* oe2 = out_edge + (((size_t)(b * NQ) + j_p) * NQ + i_p) * 5;
        #pragma unroll
        for (int q = 0; q < 5; ++q) {
            float vq = b_eo2[q] + oBuf[(0 * 64 + p) * 5 + q] + oBuf[(1 * 64 + p) * 5 + q]
                                + oBuf[(2 * 64 + p) * 5 + q] + oBuf[(3 * 64 + p) * 5 + q];
            vq = em ? vq : 0.0f;
            oe1[q] = vq;
            oe2[q] = vq;
        }
    }
}

extern "C" void kernel_launch(void* const* d_in, const int* in_sizes, int n_in,
                              void* d_out, int out_size, void* d_ws, size_t ws_size,
                              hipStream_t stream) {
    const float* node     = (const float*)d_in[0];
    const float* edge     = (const float*)d_in[1];
    const int*   block_id = (const int*)d_in[2];
    const void*  vm_raw   = d_in[3];
    const float* W_nt  = (const float*)d_in[4];
    const float* b_nt  = (const float*)d_in[5];
    const float* W_n1  = (const float*)d_in[6];
    const float* b_n1  = (const float*)d_in[7];
    const float* W_e1  = (const float*)d_in[8];
    const float* b_e1  = (const float*)d_in[9];
    const float* W_f1  = (const float*)d_in[10];
    const float* b_f1  = (const float*)d_in[11];
    const float* W_f2  = (const float*)d_in[12];
    const float* b_f2  = (const float*)d_in[13];
    const float* W_no1 = (const float*)d_in[14];
    const float* b_no1 = (const float*)d_in[15];
    const float* g_no  = (const float*)d_in[16];
    const float* be_no = (const float*)d_in[17];
    const float* W_no2 = (const float*)d_in[18];
    const float* b_no2 = (const float*)d_in[19];
    const float* W_eo1 = (const float*)d_in[20];
    const float* b_eo1 = (const float*)d_in[21];
    const float* g_eo  = (const float*)d_in[22];
    const float* be_eo = (const float*)d_in[23];
    const float* W_eo2 = (const float*)d_in[24];
    const float* b_eo2 = (const float*)d_in[25];

    char* ws = (char*)d_ws;
    int*   vmd   = (int*)ws;                                      // 8 KB
    float* n_ws  = (float*)(ws + 8192);                           // 1 MB
    float* q1_ws = (float*)(ws + 8192 + (1 << 20));               // 512 KB
    float* q2_ws = (float*)(ws + 8192 + (1 << 20) + (512 << 10)); // 512 KB
    float* xin_part  = (float*)(ws + 8192 + (2 << 20));           // 2 MB
    float* xout_part = (float*)(ws + 8192 + (4 << 20));           // 2 MB
    float* out_node = (float*)d_out;
    float* out_edge = out_node + 4 * 512 * 10;

    decode_mask_kernel<<<1, 256, 0, stream>>>((const unsigned char*)vm_raw, vmd, 4 * 512);
    tile_sum_kernel<<<256, 1024, 0, stream>>>(edge, block_id, vmd, xin_part, xout_part);
    node2_kernel<<<4 * 512, 128, 0, stream>>>(
        node, block_id, vmd, xin_part, xout_part,
        W_nt, b_nt, W_n1, b_n1, W_f1, b_f1, W_no1, b_no1, g_no, be_no, W_no2, b_no2,
        n_ws, q1_ws, q2_ws, out_node);
    edge_kernel<<<8192 + 16, 256, 0, stream>>>(
        edge, block_id, vmd, n_ws, q1_ws, q2_ws,
        W_e1, b_e1, W_f2, b_f2,
        W_eo1, b_eo1, g_eo, be_eo, W_eo2, b_eo2, out_edge);
}